// Round 5
// baseline (201.342 us; speedup 1.0000x reference)
//
#include <hip/hip_runtime.h>
#include <math.h>

// Problem constants (B=4, S=2048, H=1024, E=16, TOP_K=4)
constexpr int kTokens = 8192;   // B*S
constexpr int kH      = 1024;
constexpr int kE      = 16;
constexpr int kTopK   = 4;
constexpr int kNC     = 16;     // partial chunks = (modality, h-quarter)

// ---------------------------------------------------------------------------
// Stage 1: partial logits. Block = 128 threads (2 waves) = 128 tokens,
// one (modality m, 256-h range) slice. Grid = 64 token-groups x 16 slices
// = 1024 blocks. blockIdx = tg*16 + ks, so co-resident blocks (b, b+256,...)
// share ks -> identical 16 KB weight slice -> scalar-K$/L2 reuse (round 4's
// limiter was weight-fetch round-trips: 8 s_loadx16 per 256 VALU cyc with
// per-block-distinct slices thrashing K$ -> VALUBusy 19%).
// Per 16-h pass: stage x[128 tok][16 h] into double-buffered LDS (coalesced
// float4, register-pipelined); each thread owns ONE token (t = token), both
// waves consume the SAME wave-uniform 1 KB of weights -> 2048 VALU
// cyc/KB-of-weights (8x round 4's ratio). No cross-wave reduce: waves split
// tokens, not h.
// Numerics = rounds 1-4 (passed, 300x margin): fp32 accum over 64-h spans,
// fp64 fold, fp32 partial per 256-h chunk, fp64 combine in stage 2.
// ---------------------------------------------------------------------------
__global__ __launch_bounds__(128, 5)
void router_fmac(const float* __restrict__ x,   const float* __restrict__ img,
                 const float* __restrict__ txt, const float* __restrict__ aud,
                 const float* __restrict__ Wg,  const float* __restrict__ Wi,
                 const float* __restrict__ Wt,  const float* __restrict__ Wa,
                 float* __restrict__ partials)
{
    // two [128 tok][20 float] buffers (stride 80 B: 16B-aligned for b128;
    // 4-way bank aliasing = 1.58x on 4 reads/pass -> negligible). 20 KB.
    __shared__ float smem[2 * 2560];

    const int t   = threadIdx.x;        // == local token id
    const int bid = blockIdx.x;
    const int ks  = bid & 15;           // slice: m = ks>>2, h-quarter = ks&3
    const int tg  = bid >> 4;           // token group
    const int m   = ks >> 2;
    const int k0  = (ks & 3) * 256;     // h offset within modality
    const int tok0 = tg * 128;

    const float* Xm = (m == 0) ? x  : (m == 1) ? img : (m == 2) ? txt : aud;
    const float* Wm = (m == 0) ? Wg : (m == 1) ? Wi  : (m == 2) ? Wt  : Wa;

    // staging role: col sc (16 B), rows sr, sr+32, sr+64, sr+96 -> each
    // wave-instr reads 16 consecutive 64-B row-segments (coalesced).
    const int sc = t & 3;
    const int sr = t >> 2;              // 0..31

    float4 pf[4];

    // ---- prologue: stage pass 0 ----
    {
        const float* src = Xm + (size_t)(tok0 + sr) * kH + k0 + sc * 4;
#pragma unroll
        for (int it = 0; it < 4; ++it)
            pf[it] = *(const float4*)(src + (size_t)(it * 32) * kH);
#pragma unroll
        for (int it = 0; it < 4; ++it)
            *(float4*)&smem[(sr + it * 32) * 20 + sc * 4] = pf[it];
    }
    __syncthreads();

    double dacc[kE];
#pragma unroll
    for (int e = 0; e < kE; ++e) dacc[e] = 0.0;
    float facc[kE];

    for (int p = 0; p < 16; ++p) {      // 16 passes x 16 h = 256 h
        // issue next pass's global loads (in flight during compute)
        if (p < 15) {
            const float* src = Xm + (size_t)(tok0 + sr) * kH + k0 + (p + 1) * 16 + sc * 4;
#pragma unroll
            for (int it = 0; it < 4; ++it)
                pf[it] = *(const float4*)(src + (size_t)(it * 32) * kH);
        }

        if ((p & 3) == 0) {
#pragma unroll
            for (int e = 0; e < kE; ++e) facc[e] = 0.f;
        }

        // x for this thread's token: 16 h from LDS
        const float* buf = smem + (p & 1) * 2560;
        float4 xv[4];
#pragma unroll
        for (int j4 = 0; j4 < 4; ++j4)
            xv[j4] = *(const float4*)&buf[t * 20 + j4 * 4];

        // weights: wave-uniform rows, identical across both waves -> s_load
        const float* wrow = Wm + (size_t)(k0 + p * 16) * kE;
#pragma unroll
        for (int j = 0; j < 16; ++j) {
            const float4 xq = xv[j >> 2];
            const int    jc = j & 3;
            const float  xh = (jc == 0) ? xq.x : (jc == 1) ? xq.y : (jc == 2) ? xq.z : xq.w;
            const float* wr = wrow + j * kE;
            const float4 w0 = *(const float4*)(wr + 0);
            const float4 w1 = *(const float4*)(wr + 4);
            const float4 w2 = *(const float4*)(wr + 8);
            const float4 w3 = *(const float4*)(wr + 12);
            facc[0]  += xh * w0.x;  facc[1]  += xh * w0.y;
            facc[2]  += xh * w0.z;  facc[3]  += xh * w0.w;
            facc[4]  += xh * w1.x;  facc[5]  += xh * w1.y;
            facc[6]  += xh * w1.z;  facc[7]  += xh * w1.w;
            facc[8]  += xh * w2.x;  facc[9]  += xh * w2.y;
            facc[10] += xh * w2.z;  facc[11] += xh * w2.w;
            facc[12] += xh * w3.x;  facc[13] += xh * w3.y;
            facc[14] += xh * w3.z;  facc[15] += xh * w3.w;
        }

        if ((p & 3) == 3) {   // fold 64-h fp32 span into fp64
#pragma unroll
            for (int e = 0; e < kE; ++e) dacc[e] += (double)facc[e];
        }

        if (p < 15) {
            float* nb = smem + ((p + 1) & 1) * 2560;
#pragma unroll
            for (int it = 0; it < 4; ++it)
                *(float4*)&nb[(sr + it * 32) * 20 + sc * 4] = pf[it];
        }
        __syncthreads();
    }

    // ---- epilogue: fp32 partial [ks][tok][e], 64 B/thread contiguous ----
    float* pp = partials + ((size_t)ks * kTokens + tok0 + t) * kE;
#pragma unroll
    for (int q = 0; q < 4; ++q) {
        *(float4*)&pp[q * 4] = make_float4((float)dacc[q * 4 + 0], (float)dacc[q * 4 + 1],
                                           (float)dacc[q * 4 + 2], (float)dacc[q * 4 + 3]);
    }
}

// ---------------------------------------------------------------------------
// Stage 2: combine 16 chunk-partials + biases (fp64), softmax, top-k, output
// writes, per-block expert sums. Block = 64 tokens x 256 threads.
// ---------------------------------------------------------------------------
__global__ __launch_bounds__(256)
void router_topk(const float* __restrict__ partials,
                 const float* __restrict__ bg, const float* __restrict__ bi,
                 const float* __restrict__ bt, const float* __restrict__ ba,
                 float* __restrict__ out, float* __restrict__ blocksum)
{
    __shared__ double lgs[64][kE + 1];
    __shared__ float  pr[64][kE + 1];

    const int t    = threadIdx.x;
    const int tq   = t >> 2;      // token offset 0..63
    const int eq   = t & 3;       // e-quad
    const int tok0 = blockIdx.x * 64;

    double a0 = (double)bg[eq*4+0] + (double)bi[eq*4+0] + (double)bt[eq*4+0] + (double)ba[eq*4+0];
    double a1 = (double)bg[eq*4+1] + (double)bi[eq*4+1] + (double)bt[eq*4+1] + (double)ba[eq*4+1];
    double a2 = (double)bg[eq*4+2] + (double)bi[eq*4+2] + (double)bt[eq*4+2] + (double)ba[eq*4+2];
    double a3 = (double)bg[eq*4+3] + (double)bi[eq*4+3] + (double)bt[eq*4+3] + (double)ba[eq*4+3];

#pragma unroll
    for (int c = 0; c < kNC; ++c) {
        const float4 v = *(const float4*)(partials + ((size_t)c * kTokens + tok0 + tq) * kE + eq * 4);
        a0 += (double)v.x;  a1 += (double)v.y;  a2 += (double)v.z;  a3 += (double)v.w;
    }
    lgs[tq][eq*4+0] = a0;  lgs[tq][eq*4+1] = a1;
    lgs[tq][eq*4+2] = a2;  lgs[tq][eq*4+3] = a3;
    __syncthreads();

    if (t < 64) {
        const int tok = tok0 + t;
        double lg[kE];
#pragma unroll
        for (int e = 0; e < kE; ++e) lg[e] = lgs[t][e];

        double mx = lg[0];
#pragma unroll
        for (int e = 1; e < kE; ++e) mx = fmax(mx, lg[e]);

        float p[kE];
        float sum = 0.f;
#pragma unroll
        for (int e = 0; e < kE; ++e) {
            p[e] = expf((float)(lg[e] - mx));
            sum += p[e];
        }
        const float inv = 1.f / sum;
#pragma unroll
        for (int e = 0; e < kE; ++e) { p[e] *= inv; pr[t][e] = p[e]; }

        // top-4, descending, ties -> smallest index (matches jax.lax.top_k)
        unsigned used = 0;
        float tp[kTopK];
        int   ti[kTopK];
        float s4 = 0.f;
#pragma unroll
        for (int k = 0; k < kTopK; ++k) {
            float best = -1.f;
            int   bidx = 0;
#pragma unroll
            for (int e = 0; e < kE; ++e) {
                if (!((used >> e) & 1u) && p[e] > best) { best = p[e]; bidx = e; }
            }
            used |= 1u << bidx;
            tp[k] = best;
            ti[k] = bidx;
            s4 += best;
        }
        const float rn = 1.f / s4;

        *(float4*)&out[(size_t)tok * kTopK] =
            make_float4((float)ti[0], (float)ti[1], (float)ti[2], (float)ti[3]);
        *(float4*)&out[(size_t)kTokens * kTopK + (size_t)tok * kTopK] =
            make_float4(tp[0] * rn, tp[1] * rn, tp[2] * rn, tp[3] * rn);
    }
    __syncthreads();

    if (t < kE) {
        float s = 0.f;
#pragma unroll
        for (int tk = 0; tk < 64; ++tk) s += pr[tk][t];
        blocksum[blockIdx.x * kE + t] = s;
    }
}

// ---------------------------------------------------------------------------
// Stage 3: 128 block-partials -> mean prob per expert -> aux loss scalar
// ---------------------------------------------------------------------------
__global__ __launch_bounds__(64)
void router_aux(const float* __restrict__ blocksum, float* __restrict__ out)
{
    __shared__ double ps[kE];
    const int t = threadIdx.x;
    if (t < kE) {
        double s = 0.0;
        for (int b = 0; b < 128; ++b) s += (double)blocksum[b * kE + t];
        ps[t] = s / (double)kTokens;
    }
    __syncthreads();
    if (t == 0) {
        double aux = 0.0;
#pragma unroll
        for (int e = 0; e < kE; ++e) aux += ps[e] * log(ps[e] * (double)kE + 1e-9);
        out[(size_t)kTokens * kTopK * 2] = (float)aux;  // element 65536
    }
}

extern "C" void kernel_launch(void* const* d_in, const int* in_sizes, int n_in,
                              void* d_out, int out_size, void* d_ws, size_t ws_size,
                              hipStream_t stream)
{
    const float* x   = (const float*)d_in[0];
    const float* img = (const float*)d_in[1];
    const float* txt = (const float*)d_in[2];
    const float* aud = (const float*)d_in[3];
    const float* Wg  = (const float*)d_in[4];
    const float* bg  = (const float*)d_in[5];
    const float* Wi  = (const float*)d_in[6];
    const float* bi  = (const float*)d_in[7];
    const float* Wt  = (const float*)d_in[8];
    const float* bt  = (const float*)d_in[9];
    const float* Wa  = (const float*)d_in[10];
    const float* ba  = (const float*)d_in[11];

    float* out      = (float*)d_out;
    float* partials = (float*)d_ws;   // 16*8192*16*4 = 8 MB (ws >= 8.4 MB proven)
    float* blocksum = (float*)((char*)d_ws + (size_t)kNC * kTokens * kE * 4);  // 8 KB

    router_fmac<<<1024, 128, 0, stream>>>(x, img, txt, aud, Wg, Wi, Wt, Wa, partials);
    router_topk<<<128, 256, 0, stream>>>(partials, bg, bi, bt, ba, out, blocksum);
    router_aux<<<1, 64, 0, stream>>>(blocksum, out);
}